// Round 7
// baseline (155.110 us; speedup 1.0000x reference)
//
#include <hip/hip_runtime.h>
#include <hip/hip_bf16.h>
#include <stdint.h>

// Problem constants (fixed by the reference)
#define N_B   16384   // batch
#define D_DIM 1024    // input dim
#define K_K   512     // mixture components
#define L_DIM 128     // latent dim
#define H_DIM 64      // phi hidden
#define SX    1032    // x_bf LDS row stride in shorts (1024 + 8 pad; balanced b128 reads)

typedef __attribute__((ext_vector_type(8))) short short8;   // 8 bf16 = 4 VGPRs (MFMA A/B frag)
typedef __attribute__((ext_vector_type(4))) float f32x4;    // MFMA C/D frag

__device__ __forceinline__ unsigned short f2bf(float f) {   // fp32 -> bf16 RNE (scalar)
    union { float f; unsigned int u; } c; c.f = f;
    unsigned int u = c.u;
    unsigned int r = (u + 0x7FFFu + ((u >> 16) & 1u)) >> 16;
    return (unsigned short)r;
}

__device__ __forceinline__ unsigned int pk2(float a, float b) {  // 2x fp32 -> packed bf16x2
    __hip_bfloat162 t = __float22bfloat162_rn(make_float2(a, b));
    union { __hip_bfloat162 h; unsigned int u; } c; c.h = t;
    return c.u;
}

// ---------------- kernel 1: prep ----------------
// 64 blocks x 256 threads. Per block: 8 components (h = relu(z@W1+b1) -> bf16,
// phi2[k] = ||h@W2+b2||^2 exact fp32), plus 1/64th of W2 -> bf16 conversion.
__global__ __launch_bounds__(256) void prep_kernel(
    const float* __restrict__ z, const float* __restrict__ W1,
    const float* __restrict__ b1, const float* __restrict__ W2,
    const float* __restrict__ b2, unsigned short* __restrict__ W2bf,
    unsigned short* __restrict__ h_bf, float* __restrict__ phi2) {
    __shared__ float zsh[8][L_DIM];     // 4 KB
    __shared__ float hsh[8][H_DIM];     // 2 KB
    __shared__ float redp[4][8];
    const int tid = threadIdx.x;
    const int k0 = blockIdx.x * 8;

    // --- W2 -> bf16: 64 blocks x 256 threads x 1 float4 = 16384 float4 = all of W2
    {
        int i = blockIdx.x * 256 + tid;
        float4 v = ((const float4*)W2)[i];
        uint2 o = make_uint2(pk2(v.x, v.y), pk2(v.z, v.w));
        *(uint2*)(W2bf + i * 4) = o;
    }
    // --- stage z rows for this block's 8 components
#pragma unroll
    for (int c = 0; c < 4; ++c) {
        int idx = c * 256 + tid;
        zsh[idx >> 7][idx & 127] = z[k0 * L_DIM + idx];
    }
    __syncthreads();
    // --- h = relu(z@W1+b1): thread t handles comps (t>>6) and (t>>6)+4 at col t&63
    {
        const int j = tid & 63, kk = tid >> 6;
        float bb = b1[j];
        float s0 = bb, s1 = bb;
        for (int l = 0; l < L_DIM; ++l) {
            float w = W1[l * H_DIM + j];
            s0 += zsh[kk][l] * w;
            s1 += zsh[kk + 4][l] * w;
        }
        float h0 = fmaxf(s0, 0.0f), h1 = fmaxf(s1, 0.0f);
        hsh[kk][j] = h0; hsh[kk + 4][j] = h1;
        h_bf[(k0 + kk) * H_DIM + j]     = f2bf(h0);
        h_bf[(k0 + kk + 4) * H_DIM + j] = f2bf(h1);
    }
    __syncthreads();
    // --- phi2[k] = ||h@W2 + b2||^2, exact fp32
    float ss[8] = {0.f, 0.f, 0.f, 0.f, 0.f, 0.f, 0.f, 0.f};
#pragma unroll
    for (int c = 0; c < 4; ++c) {
        int d = c * 256 + tid;
        float bb = b2[d];
        float a[8];
#pragma unroll
        for (int kk = 0; kk < 8; ++kk) a[kk] = bb;
        for (int j = 0; j < H_DIM; ++j) {
            float w = W2[j * D_DIM + d];
#pragma unroll
            for (int kk = 0; kk < 8; ++kk) a[kk] += hsh[kk][j] * w;
        }
#pragma unroll
        for (int kk = 0; kk < 8; ++kk) ss[kk] += a[kk] * a[kk];
    }
    const int lane = tid & 63, wv = tid >> 6;
#pragma unroll
    for (int kk = 0; kk < 8; ++kk) {
        float v = ss[kk];
#pragma unroll
        for (int o = 1; o < 64; o <<= 1) v += __shfl_xor(v, o, 64);
        if (lane == 0) redp[wv][kk] = v;
    }
    __syncthreads();
    if (tid < 8) phi2[k0 + tid] = redp[0][tid] + redp[1][tid] + redp[2][tid] + redp[3][tid];
}

// ---------------- main kernel: per block = one 16-row batch tile ----------------
// 1024 blocks x 256 threads, ~38 KB LDS, VGPR<=128 -> 4 blocks/CU = 16 waves/CU.
// Staging: strictly linear float4 loads in explicit batches of 8 independent
// loads (no consumer between issues) -> 8 outstanding loads/wave x 16 waves/CU.
// Stage 1: wave w computes u[:, 16w:16w+16] (A-frags from LDS bf16 x tile,
// W2 B-frags L2-hot global). Stage 2: S = h @ u^T + fused exp/log/mean.
__global__ __launch_bounds__(256, 4) void main_kernel(
    const float* __restrict__ x, const unsigned short* __restrict__ W2bf,
    const unsigned short* __restrict__ h_bf, const float* __restrict__ phi2,
    const float* __restrict__ b2, float* __restrict__ out) {
    __shared__ __align__(16) unsigned short x_bf[16 * SX];      // 33 KB bf16 x tile
    __shared__ __align__(16) unsigned short u_tile[16 * 72];    // 2.25 KB, stride 72
    __shared__ float phi2s[K_K];                                // 2 KB
    __shared__ float x2s[16], xb2s[16];                         // 128 B
    __shared__ float red[4][16];                                // 256 B

    const int tid = threadIdx.x;
    const int wv  = tid >> 6;      // wave 0..3
    const int l   = tid & 63;      // lane
    const int lm  = l & 15;
    const int q   = l >> 4;        // quad 0..3
    const int n0  = blockIdx.x * 16;

    // b2 slices for the xb2 dot: lane l covers cols sub*256 + l*4 (coalesced)
    float4 b2r[4];
#pragma unroll
    for (int sub = 0; sub < 4; ++sub)
        b2r[sub] = ((const float4*)b2)[sub * 64 + l];

    // phi2 stage (overlaps x loads below)
    phi2s[tid]       = phi2[tid];
    phi2s[256 + tid] = phi2[256 + tid];

    // ---- stage x tile: wave wv owns rows {s*4+wv}, linear 1-KB chunks ----
    // two half-passes; each issues 8 INDEPENDENT float4 loads, then consumes.
    float x2a[4] = {0.f, 0.f, 0.f, 0.f}, xba[4] = {0.f, 0.f, 0.f, 0.f};
#pragma unroll
    for (int half = 0; half < 2; ++half) {
        float4 xv[8];
#pragma unroll
        for (int s = 0; s < 4; ++s)
#pragma unroll
            for (int p = 0; p < 2; ++p) {
                const int sub = half * 2 + p;
                xv[s * 2 + p] = *(const float4*)(x + (size_t)(n0 + s * 4 + wv) * D_DIM + sub * 256 + l * 4);
            }
#pragma unroll
        for (int s = 0; s < 4; ++s)
#pragma unroll
            for (int p = 0; p < 2; ++p) {
                const int sub = half * 2 + p;
                float4 v = xv[s * 2 + p];
                x2a[s] += v.x*v.x + v.y*v.y + v.z*v.z + v.w*v.w;
                xba[s] += v.x*b2r[sub].x + v.y*b2r[sub].y + v.z*b2r[sub].z + v.w*b2r[sub].w;
                uint2 o = make_uint2(pk2(v.x, v.y), pk2(v.z, v.w));
                *(uint2*)&x_bf[(s * 4 + wv) * SX + sub * 256 + l * 4] = o;
            }
    }
    // per-row reduce of x2/xb2 (rows uniquely owned by this wave -> no atomics)
#pragma unroll
    for (int s = 0; s < 4; ++s) {
        float a = x2a[s], b = xba[s];
#pragma unroll
        for (int o = 1; o < 64; o <<= 1) { a += __shfl_xor(a, o, 64); b += __shfl_xor(b, o, 64); }
        if (l == 0) { x2s[s * 4 + wv] = a; xb2s[s * 4 + wv] = b; }
    }
    __syncthreads();

    // ---- stage 1: u[:, wv*16:+16] = x @ W2^T over full K=1024 ----
    f32x4 c1 = {};
    const unsigned short* w2row = W2bf + (size_t)(wv * 16 + lm) * D_DIM;
#pragma unroll
    for (int ks = 0; ks < 32; ++ks) {
        const int k0 = ks * 32 + q * 8;
        short8 bw = *(const short8*)(w2row + k0);                 // L2-hot global
        short8 a0 = *(const short8*)&x_bf[lm * SX + k0];          // x rows 0..15 (LDS)
        c1 = __builtin_amdgcn_mfma_f32_16x16x32_bf16(a0, bw, c1, 0, 0, 0);
    }
    // write this wave's 16 u columns (C layout: row = q*4 + r, col = wv*16+lm)
#pragma unroll
    for (int r = 0; r < 4; ++r)
        u_tile[(q * 4 + r) * 72 + wv * 16 + lm] = f2bf(c1[r]);
    __syncthreads();

    // ---- stage 2: S = h @ u^T, wave wv covers component rows [wv*128, wv*128+128) ----
    f32x4 acc[8] = {};
#pragma unroll
    for (int ks = 0; ks < 2; ++ks) {
        const int ko = ks * 32 + q * 8;
        short8 bfr = *(const short8*)&u_tile[lm * 72 + ko];       // u rows = batch cols
#pragma unroll
        for (int i = 0; i < 8; ++i) {
            short8 a = *(const short8*)(h_bf + (size_t)(wv * 128 + i * 16 + lm) * H_DIM + ko);
            acc[i] = __builtin_amdgcn_mfma_f32_16x16x32_bf16(a, bfr, acc[i], 0, 0, 0);
        }
    }
    // ---- epilogue: sq = phi2[m] + (x2[n] - 2*xb2[n]) - 2*S; sum_k exp(-sq) ----
    float xn = x2s[lm] - 2.f * xb2s[lm];
    float cs = 0.f;
#pragma unroll
    for (int i = 0; i < 8; ++i) {
#pragma unroll
        for (int r = 0; r < 4; ++r) {
            float p2 = phi2s[wv * 128 + i * 16 + q * 4 + r];
            cs += __expf(-(p2 + xn - 2.f * acc[i][r]));
        }
    }
    cs += __shfl_xor(cs, 16, 64); cs += __shfl_xor(cs, 32, 64);
    if (l < 16) red[wv][l] = cs;
    __syncthreads();
    // ---- fused final reduction: mean over this block's 16 rows of log(mean_k lik + eps)
    if (tid < 16) {
        float row_lik = red[0][tid] + red[1][tid] + red[2][tid] + red[3][tid];
        float lg = __logf(row_lik * (1.0f / (float)K_K) + 1e-9f);
        lg += __shfl_xor(lg, 1, 64);
        lg += __shfl_xor(lg, 2, 64);
        lg += __shfl_xor(lg, 4, 64);
        lg += __shfl_xor(lg, 8, 64);
        if (tid == 0) atomicAdd(out, lg * (1.0f / (float)N_B));
    }
}

extern "C" void kernel_launch(void* const* d_in, const int* in_sizes, int n_in,
                              void* d_out, int out_size, void* d_ws, size_t ws_size,
                              hipStream_t stream) {
    const float* x  = (const float*)d_in[0];
    const float* z  = (const float*)d_in[1];
    const float* W1 = (const float*)d_in[2];
    const float* b1 = (const float*)d_in[3];
    const float* W2 = (const float*)d_in[4];
    const float* b2 = (const float*)d_in[5];

    char* ws = (char*)d_ws;
    unsigned short* W2bf = (unsigned short*)(ws);            // 128 KB
    unsigned short* h_bf = (unsigned short*)(ws + 131072);   // 64 KB
    float*          phi2 = (float*)(ws + 196608);            // 2 KB

    hipMemsetAsync(d_out, 0, sizeof(float), stream);
    prep_kernel<<<64, 256, 0, stream>>>(z, W1, b1, W2, b2, W2bf, h_bf, phi2);
    main_kernel<<<N_B / 16, 256, 0, stream>>>(x, W2bf, h_bf, phi2, b2, (float*)d_out);
}

// Round 8
// 144.233 us; speedup vs baseline: 1.0754x; 1.0754x over previous
//
#include <hip/hip_runtime.h>
#include <hip/hip_bf16.h>
#include <stdint.h>

// Problem constants (fixed by the reference)
#define N_B   16384   // batch
#define D_DIM 1024    // input dim
#define K_K   512     // mixture components
#define L_DIM 128     // latent dim
#define H_DIM 64      // phi hidden
#define SX    1032    // x_bf LDS row stride in shorts (1024 + 8 pad; balanced b128 reads)

typedef __attribute__((ext_vector_type(8))) short short8;   // 8 bf16 = 4 VGPRs (MFMA A/B frag)
typedef __attribute__((ext_vector_type(4))) float f32x4;    // MFMA C/D frag

__device__ __forceinline__ unsigned short f2bf(float f) {   // fp32 -> bf16 RNE (scalar)
    union { float f; unsigned int u; } c; c.f = f;
    unsigned int u = c.u;
    unsigned int r = (u + 0x7FFFu + ((u >> 16) & 1u)) >> 16;
    return (unsigned short)r;
}

__device__ __forceinline__ unsigned int pk2(float a, float b) {  // 2x fp32 -> packed bf16x2
    __hip_bfloat162 t = __float22bfloat162_rn(make_float2(a, b));
    union { __hip_bfloat162 h; unsigned int u; } c; c.h = t;
    return c.u;
}

// ---------------- kernel 1: prep ----------------
// 64 blocks x 256 threads. Per block: 8 components (h = relu(z@W1+b1) -> bf16,
// phi2[k] = ||h@W2+b2||^2 exact fp32), plus 1/64th of W2 -> bf16 conversion.
__global__ __launch_bounds__(256) void prep_kernel(
    const float* __restrict__ z, const float* __restrict__ W1,
    const float* __restrict__ b1, const float* __restrict__ W2,
    const float* __restrict__ b2, unsigned short* __restrict__ W2bf,
    unsigned short* __restrict__ h_bf, float* __restrict__ phi2) {
    __shared__ float zsh[8][L_DIM];     // 4 KB
    __shared__ float hsh[8][H_DIM];     // 2 KB
    __shared__ float redp[4][8];
    const int tid = threadIdx.x;
    const int k0 = blockIdx.x * 8;

    // --- W2 -> bf16: 64 blocks x 256 threads x 1 float4 = 16384 float4 = all of W2
    {
        int i = blockIdx.x * 256 + tid;
        float4 v = ((const float4*)W2)[i];
        uint2 o = make_uint2(pk2(v.x, v.y), pk2(v.z, v.w));
        *(uint2*)(W2bf + i * 4) = o;
    }
    // --- stage z rows for this block's 8 components
#pragma unroll
    for (int c = 0; c < 4; ++c) {
        int idx = c * 256 + tid;
        zsh[idx >> 7][idx & 127] = z[k0 * L_DIM + idx];
    }
    __syncthreads();
    // --- h = relu(z@W1+b1): thread t handles comps (t>>6) and (t>>6)+4 at col t&63
    {
        const int j = tid & 63, kk = tid >> 6;
        float bb = b1[j];
        float s0 = bb, s1 = bb;
        for (int l = 0; l < L_DIM; ++l) {
            float w = W1[l * H_DIM + j];
            s0 += zsh[kk][l] * w;
            s1 += zsh[kk + 4][l] * w;
        }
        float h0 = fmaxf(s0, 0.0f), h1 = fmaxf(s1, 0.0f);
        hsh[kk][j] = h0; hsh[kk + 4][j] = h1;
        h_bf[(k0 + kk) * H_DIM + j]     = f2bf(h0);
        h_bf[(k0 + kk + 4) * H_DIM + j] = f2bf(h1);
    }
    __syncthreads();
    // --- phi2[k] = ||h@W2 + b2||^2, exact fp32
    float ss[8] = {0.f, 0.f, 0.f, 0.f, 0.f, 0.f, 0.f, 0.f};
#pragma unroll
    for (int c = 0; c < 4; ++c) {
        int d = c * 256 + tid;
        float bb = b2[d];
        float a[8];
#pragma unroll
        for (int kk = 0; kk < 8; ++kk) a[kk] = bb;
        for (int j = 0; j < H_DIM; ++j) {
            float w = W2[j * D_DIM + d];
#pragma unroll
            for (int kk = 0; kk < 8; ++kk) a[kk] += hsh[kk][j] * w;
        }
#pragma unroll
        for (int kk = 0; kk < 8; ++kk) ss[kk] += a[kk] * a[kk];
    }
    const int lane = tid & 63, wv = tid >> 6;
#pragma unroll
    for (int kk = 0; kk < 8; ++kk) {
        float v = ss[kk];
#pragma unroll
        for (int o = 1; o < 64; o <<= 1) v += __shfl_xor(v, o, 64);
        if (lane == 0) redp[wv][kk] = v;
    }
    __syncthreads();
    if (tid < 8) phi2[k0 + tid] = redp[0][tid] + redp[1][tid] + redp[2][tid] + redp[3][tid];
}

// ---------------- main kernel: per block = one 32-row batch tile ----------------
// 512 blocks x 256 threads, 66 KB LDS -> 2 blocks/CU (8 waves). Staging: wave wv
// owns the contiguous 32-KB span rows [wv*8, wv*8+8); 2 batches x 16 INDEPENDENT
// linear float4 loads (consume only after the whole batch is issued -> 2 latency
// exposures instead of 8). Stage 1: u[:, wv*16:+16] = x @ W2^T with a ring-8
// register pipeline on the L2-hot W2 fragments (8 loads in flight ahead of use).
// Stage 2: S = h @ u^T (512x32) + fused exp / component-sum / log / mean.
__global__ __launch_bounds__(256) void main_kernel(
    const float* __restrict__ x, const unsigned short* __restrict__ W2bf,
    const unsigned short* __restrict__ h_bf, const float* __restrict__ phi2,
    const float* __restrict__ b2, float* __restrict__ out) {
    __shared__ __align__(16) unsigned short x_bf[32 * SX];      // 66 KB bf16 x tile
    __shared__ __align__(16) unsigned short u_tile[32 * 72];    // 4.5 KB, stride 72
    __shared__ float phi2s[K_K];                                // 2 KB
    __shared__ float x2s[32], xb2s[32];                         // 256 B
    __shared__ float red[4][32];                                // 512 B

    const int tid = threadIdx.x;
    const int wv  = tid >> 6;      // wave 0..3
    const int l   = tid & 63;      // lane
    const int lm  = l & 15;
    const int q   = l >> 4;        // quad 0..3
    const int n0  = blockIdx.x * 32;

    // b2 slices for the xb2 dot: lane l covers cols sub*256 + l*4 (coalesced)
    float4 b2r[4];
#pragma unroll
    for (int sub = 0; sub < 4; ++sub)
        b2r[sub] = ((const float4*)b2)[sub * 64 + l];

    // phi2 stage (overlaps x loads below)
    phi2s[tid]       = phi2[tid];
    phi2s[256 + tid] = phi2[256 + tid];

    // ---- stage x tile: wave wv owns rows [wv*8, wv*8+8), contiguous 32 KB ----
    // two batches; each issues 16 INDEPENDENT float4 loads (rows r0..r0+3 x 4 subs),
    // then consumes (exact fp32 x2/xb2 + bf16 pack -> LDS).
    float x2a[8], xba[8];
#pragma unroll
    for (int batch = 0; batch < 2; ++batch) {
        const int r0 = wv * 8 + batch * 4;
        float4 xv[16];
#pragma unroll
        for (int s = 0; s < 4; ++s)
#pragma unroll
            for (int sub = 0; sub < 4; ++sub)
                xv[s * 4 + sub] = *(const float4*)(x + (size_t)(n0 + r0 + s) * D_DIM + sub * 256 + l * 4);
#pragma unroll
        for (int s = 0; s < 4; ++s) {
            float s2 = 0.f, sb = 0.f;
#pragma unroll
            for (int sub = 0; sub < 4; ++sub) {
                float4 v = xv[s * 4 + sub];
                s2 += v.x*v.x + v.y*v.y + v.z*v.z + v.w*v.w;
                sb += v.x*b2r[sub].x + v.y*b2r[sub].y + v.z*b2r[sub].z + v.w*b2r[sub].w;
                uint2 o = make_uint2(pk2(v.x, v.y), pk2(v.z, v.w));
                *(uint2*)&x_bf[(r0 + s) * SX + sub * 256 + l * 4] = o;
            }
            x2a[batch * 4 + s] = s2; xba[batch * 4 + s] = sb;
        }
    }
    // per-row reduce of x2/xb2 (rows uniquely owned by this wave -> no atomics)
#pragma unroll
    for (int s = 0; s < 8; ++s) {
        float a = x2a[s], b = xba[s];
#pragma unroll
        for (int o = 1; o < 64; o <<= 1) { a += __shfl_xor(a, o, 64); b += __shfl_xor(b, o, 64); }
        if (l == 0) { x2s[wv * 8 + s] = a; xb2s[wv * 8 + s] = b; }
    }
    __syncthreads();

    // ---- stage 1: u[:, wv*16:+16] = x @ W2^T over full K=1024, W2 ring-8 ----
    const unsigned short* w2row = W2bf + (size_t)(wv * 16 + lm) * D_DIM + q * 8;
    short8 wf[8];
#pragma unroll
    for (int p = 0; p < 8; ++p)
        wf[p] = *(const short8*)(w2row + p * 32);
    f32x4 c1[2] = {};
#pragma unroll
    for (int ks = 0; ks < 32; ++ks) {
        const int k0 = ks * 32 + q * 8;
        short8 bw = wf[ks & 7];
        if (ks < 24)
            wf[ks & 7] = *(const short8*)(w2row + (ks + 8) * 32);
        short8 a0 = *(const short8*)&x_bf[lm * SX + k0];          // x rows 0..15
        short8 a1 = *(const short8*)&x_bf[(16 + lm) * SX + k0];   // x rows 16..31
        c1[0] = __builtin_amdgcn_mfma_f32_16x16x32_bf16(a0, bw, c1[0], 0, 0, 0);
        c1[1] = __builtin_amdgcn_mfma_f32_16x16x32_bf16(a1, bw, c1[1], 0, 0, 0);
    }
    // write this wave's 16 u columns (C layout: row = i*16 + q*4 + r, col = wv*16+lm)
#pragma unroll
    for (int i = 0; i < 2; ++i)
#pragma unroll
        for (int r = 0; r < 4; ++r)
            u_tile[(i * 16 + q * 4 + r) * 72 + wv * 16 + lm] = f2bf(c1[i][r]);
    __syncthreads();

    // ---- stage 2: S = h @ u^T, wave wv covers component rows [wv*128, wv*128+128) ----
    f32x4 acc[8][2] = {};
#pragma unroll
    for (int ks = 0; ks < 2; ++ks) {
        const int ko = ks * 32 + q * 8;
        short8 bfr[2];
#pragma unroll
        for (int j = 0; j < 2; ++j)
            bfr[j] = *(const short8*)&u_tile[(j * 16 + lm) * 72 + ko];
#pragma unroll
        for (int i = 0; i < 8; ++i) {
            short8 a = *(const short8*)(h_bf + (size_t)(wv * 128 + i * 16 + lm) * H_DIM + ko);
#pragma unroll
            for (int j = 0; j < 2; ++j)
                acc[i][j] = __builtin_amdgcn_mfma_f32_16x16x32_bf16(a, bfr[j], acc[i][j], 0, 0, 0);
        }
    }
    // ---- epilogue: sq = phi2[m] + (x2[n] - 2*xb2[n]) - 2*S; sum_k exp(-sq) ----
    float xn0 = x2s[lm]      - 2.f * xb2s[lm];
    float xn1 = x2s[16 + lm] - 2.f * xb2s[16 + lm];
    float cs0 = 0.f, cs1 = 0.f;
#pragma unroll
    for (int i = 0; i < 8; ++i) {
#pragma unroll
        for (int r = 0; r < 4; ++r) {
            float p2 = phi2s[wv * 128 + i * 16 + q * 4 + r];
            cs0 += __expf(-(p2 + xn0 - 2.f * acc[i][0][r]));
            cs1 += __expf(-(p2 + xn1 - 2.f * acc[i][1][r]));
        }
    }
    cs0 += __shfl_xor(cs0, 16, 64); cs0 += __shfl_xor(cs0, 32, 64);
    cs1 += __shfl_xor(cs1, 16, 64); cs1 += __shfl_xor(cs1, 32, 64);
    if (l < 16) { red[wv][l] = cs0; red[wv][16 + l] = cs1; }
    __syncthreads();
    // ---- fused final reduction: mean over this block's 32 rows of log(mean_k lik + eps)
    if (tid < 32) {
        float row_lik = red[0][tid] + red[1][tid] + red[2][tid] + red[3][tid];
        float lg = __logf(row_lik * (1.0f / (float)K_K) + 1e-9f);
        lg += __shfl_xor(lg, 1, 64);
        lg += __shfl_xor(lg, 2, 64);
        lg += __shfl_xor(lg, 4, 64);
        lg += __shfl_xor(lg, 8, 64);
        lg += __shfl_xor(lg, 16, 64);
        if (tid == 0) atomicAdd(out, lg * (1.0f / (float)N_B));
    }
}

extern "C" void kernel_launch(void* const* d_in, const int* in_sizes, int n_in,
                              void* d_out, int out_size, void* d_ws, size_t ws_size,
                              hipStream_t stream) {
    const float* x  = (const float*)d_in[0];
    const float* z  = (const float*)d_in[1];
    const float* W1 = (const float*)d_in[2];
    const float* b1 = (const float*)d_in[3];
    const float* W2 = (const float*)d_in[4];
    const float* b2 = (const float*)d_in[5];

    char* ws = (char*)d_ws;
    unsigned short* W2bf = (unsigned short*)(ws);            // 128 KB
    unsigned short* h_bf = (unsigned short*)(ws + 131072);   // 64 KB
    float*          phi2 = (float*)(ws + 196608);            // 2 KB

    hipMemsetAsync(d_out, 0, sizeof(float), stream);
    prep_kernel<<<64, 256, 0, stream>>>(z, W1, b1, W2, b2, W2bf, h_bf, phi2);
    main_kernel<<<N_B / 32, 256, 0, stream>>>(x, W2bf, h_bf, phi2, b2, (float*)d_out);
}